// Round 14
// baseline (253.163 us; speedup 1.0000x reference)
//
#include <hip/hip_runtime.h>

// Gated SPN, reverse scan over W:
//   h(i,t) = a*x + g1*h(i-1,t+1) + g2*h(i,t+1) + g3*h(i+1,t+1), a = 1-g1-g2-g3
//
// r14: register-free deep-queue staging via global_load_lds (width 4).
// Per tile, each of 6 waves issues 52 DMA loads (312 total = 4 arrays x 312
// slots x 16 cols, f32) into the spare LDS buffer; s_waitcnt vmcnt(52) at the
// top of the next tile waits ONLY for the previous tile, leaving 52 in
// flight across the whole scan (T3/T4 counted-vmcnt template). No staging
// registers -> compiler cannot sink loads; per-CU outstanding bytes go from
// ~4KB to ~80KB. LDS layout per slot: 64 floats = 16 cols x {x,g1,g2,g3}
// interleaved, col-position XOR-swizzled (p = q ^ (slot&15)); the per-lane
// GLOBAL source address is pre-swizzled to match (m173 both-sides rule), so
// scan reads one bank-spread ds_read_b128 per step. Normalization moved into
// the scan (same total VALU). Halo slots re-zeroed each tile by uniform
// whole-instr reads of a 256B zero region in d_ws.
// Geometry (proven r6/r13): 512 blocks = 128 slices x 2 W-chunks x 2 H-halves,
// WT=16, W-warmup 32 cols, H-halo 12 rows, per-wave DPP cones re-anchored
// every 8 steps via parity h-lines. LDS dbuf 2x78KB + h-lines = 158.4KB.

#define HH 512
#define WW 512
#define WT 16
#define NT 384              // 6 waves
#define SLOTS 312           // 8 lo-halo + 268 rows + 28 hi-halo/pad (zeroed)
#define NROW 268            // computed real rows (256 out + 12 H-halo)
#define HLN 304
#define NTILE 17
#define IPW 52              // DMA instrs per wave per tile (312/6)
#define BUFB (SLOTS * 256)  // bytes per tile buffer (79872)

typedef __attribute__((address_space(3))) void       as3_void;
typedef const __attribute__((address_space(1))) void as1_cvoid;

__device__ __forceinline__ void gl_lds4(const void* g, void* l) {
    __builtin_amdgcn_global_load_lds((as1_cvoid*)g, (as3_void*)l, 4, 0, 0);
}

__device__ __forceinline__ float dpp_prev(float v) {   // lane i <- lane i-1
    return __int_as_float(__builtin_amdgcn_update_dpp(
        0, __float_as_int(v), 0x138, 0xf, 0xf, false)); // wave_shr:1, edge->0
}
__device__ __forceinline__ float dpp_next(float v) {   // lane i <- lane i+1
    return __int_as_float(__builtin_amdgcn_update_dpp(
        0, __float_as_int(v), 0x130, 0xf, 0xf, false)); // wave_shl:1, edge->0
}

// LDS-only barrier: drains lgkm, leaves vmem (DMA queue) in flight.
__device__ __forceinline__ void lds_barrier() {
    asm volatile("s_waitcnt lgkmcnt(0)" ::: "memory");
    __builtin_amdgcn_s_barrier();
    __builtin_amdgcn_sched_barrier(0);
}

__global__ __launch_bounds__(NT) void spn_kernel(
    const float* __restrict__ X, const float* __restrict__ G1,
    const float* __restrict__ G2, const float* __restrict__ G3,
    float* __restrict__ OUT, const float* __restrict__ ZB)
{
    extern __shared__ char smem[];
    float* hlA = (float*)(smem + 2 * BUFB);   // [HLN] x2 parity h-lines
    float* hlB = hlA + HLN;

    const int tid = threadIdx.x;
    const int wv  = tid >> 6;
    const int L   = tid & 63;
    const int qp  = L >> 2;            // DMA: this lane's col-position 0..15
    const int al  = L & 3;             // DMA: this lane's array 0..3
    // scan identity (r13 cone structure)
    const int cr   = 48 * wv + L - 8;  // -8 .. 295
    const int slot = cr + 8;           // 0 .. 303
    const bool owned = (L >= 8) && (L < 56);
    const int sm  = slot & 15;         // read-side XOR swizzle key
    const int sfb = slot * 16;         // float4 index base of this slot's row

    const int slice = blockIdx.x >> 2;
    const int wch   = blockIdx.x & 1;
    const int hch   = (blockIdx.x >> 1) & 1;
    const int cend  = wch ? WW : 272;          // 17 tiles each
    const int warm  = wch ? 0 : 2;             // wch0: 32 warmup cols
    const int hb    = hch ? (HH - NROW) : 0;   // 0 or 244
    const int out_lo = hch ? 256 : 0;
    const int out_hi = hch ? 512 : 256;
    const int crg   = hb + cr;
    const bool do_store = owned && (crg >= out_lo) && (crg < out_hi);

    const size_t base = (size_t)slice * (size_t)(HH * WW);
    const float* Ap[4] = { X + base, G1 + base, G2 + base, G3 + base };
    const float* gsel = Ap[al];        // per-lane array pointer (constant)
    float* Op = OUT + base;

    // zero h-lines (visible at first lds_barrier)
    for (int i = tid; i < 2 * HLN; i += NT) hlA[i] = 0.0f;

    // ---- DMA issue: tile with left col w0 into buffer bw ----
    // instr i (0..311) covers LDS slot i: 64 floats = cols x arrays.
    // lane L writes word (qp*4 + al) of the slot; its global source is
    // array al, row (hb+i-8), col w0 + (qp ^ (i&15)). Halo slots (i<8 or
    // i>=276) read a 256B zero region instead (uniform per instr).
    auto issue_tile = [&](int w0, int bw) {
        char* bufb = smem + bw * BUFB;
        const float* gb = gsel + ((size_t)(hb - 8) * WW + w0);
        #pragma unroll 4
        for (int k = 0; k < IPW; ++k) {
            const int i = IPW * wv + k;
            const bool zero = (i < 8) || (i >= 276);
            const float* src = zero ? (ZB + L)
                                    : (gb + (size_t)i * WW + (qp ^ (i & 15)));
            gl_lds4(src, bufb + i * 256 + L * 4);
        }
    };

    // prologue: tile 0 into buf 0
    issue_tile(cend - WT, 0);

    for (int t = 0; t < NTILE; ++t) {
        const int w0 = cend - WT * (t + 1);
        const bool emit = (t >= warm);

        // issue next tile into the spare buffer, then wait ONLY for tile t
        if (t + 1 < NTILE) {
            issue_tile(w0 - WT, (t + 1) & 1);
            asm volatile("s_waitcnt vmcnt(52)" ::: "memory");
        } else {
            asm volatile("s_waitcnt vmcnt(0)" ::: "memory");
        }
        lds_barrier();   // all waves' tile-t DMA landed; h-lines visible

        const float4* T = (const float4*)(smem + (t & 1) * BUFB);

        // ---- scan: 2 sub-phases x 8 barrier-free DPP steps ----
        float hv[WT];
        #pragma unroll
        for (int sub = 0; sub < 2; ++sub) {
            const float* rd = sub ? hlB : hlA;
            float*       wr = sub ? hlA : hlB;
            float h = rd[slot];
            #pragma unroll
            for (int s = 0; s < 8; ++s) {
                const int q = 15 - 8 * sub - s;
                const float4 v = T[sfb + (q ^ sm)];   // {x, g1, g2, g3}
                const float sa = fabsf(v.y) + fabsf(v.z) + fabsf(v.w);
                const float sc = (sa >= 1.0f) ? __builtin_amdgcn_rcpf(sa) : 1.0f;
                const float n1 = v.y * sc, n2 = v.z * sc, n3 = v.w * sc;
                const float ax = (1.0f - n1 - n2 - n3) * v.x;
                const float hu = dpp_prev(h);
                const float hd = dpp_next(h);
                h = fmaf(n1, hu, fmaf(n2, h, fmaf(n3, hd, ax)));
                hv[q] = h;
            }
            if (owned) wr[slot] = h;
            lds_barrier();   // re-anchor line visible; also closes tile reads
        }

        // ---- 64B contiguous output stores ----
        if (do_store && emit) {
            float* bo = Op + (size_t)crg * WW + (size_t)w0;
            #pragma unroll
            for (int j = 0; j < 4; ++j)
                *(float4*)(bo + 4 * j) = make_float4(hv[4 * j + 0], hv[4 * j + 1],
                                                     hv[4 * j + 2], hv[4 * j + 3]);
        }
    }
}

extern "C" void kernel_launch(void* const* d_in, const int* in_sizes, int n_in,
                              void* d_out, int out_size, void* d_ws, size_t ws_size,
                              hipStream_t stream) {
    const float* X  = (const float*)d_in[0];
    const float* G1 = (const float*)d_in[1];
    const float* G2 = (const float*)d_in[2];
    const float* G3 = (const float*)d_in[3];
    float* OUT = (float*)d_out;
    float* ZB = (float*)d_ws;

    // 256B zero source for halo-slot DMA (captured graph node, deterministic)
    hipMemsetAsync(ZB, 0, 256, stream);

    const int nblocks = 4 * 32 * 2 * 2;   // 128 slices x 2 W-chunks x 2 H-halves
    const size_t smem = (size_t)2 * BUFB + 2 * HLN * sizeof(float);  // 162176B

    (void)hipFuncSetAttribute((const void*)spn_kernel,
                              hipFuncAttributeMaxDynamicSharedMemorySize, (int)smem);

    spn_kernel<<<nblocks, NT, smem, stream>>>(X, G1, G2, G3, OUT, ZB);
}

// Round 15
// 164.481 us; speedup vs baseline: 1.5392x; 1.5392x over previous
//
#include <hip/hip_runtime.h>

// Gated SPN, reverse scan over W:
//   h(i,t) = a*x + g1*h(i-1,t+1) + g2*h(i,t+1) + g3*h(i+1,t+1), a = 1-g1-g2-g3
//
// r15 = r13 geometry + WT=64 column tiles -> 256B-contiguous HBM requests
// (granule ladder 32/64/128B = 3.2/2.9/4.6 TB/s effective; this tests 256B).
// 512 blocks = 128 slices x 2 W-chunks x 2 H-halves; 268 computed rows per
// block (256 out + 12 H-halo, error ~3^-12); W: wch0 scans [0,320) with a
// 64-col warmup tile, wch1 scans [256,512) exact. fp16-packed coeff tile
// [64 w][305 slots] = 156.2KB + h-lines -> 158.6KB LDS, 1 blk/CU.
// NT=768: all 12 waves stage (16 lanes x float4 = 256B per row per array);
// waves 0-5 scan via r13's DPP cones (8 sub-phases x 8 steps, parity
// h-lines re-anchored through LDS); waves 6-11 mirror barriers only.
// Stores: 256B contiguous per owned row per tile.

#define HH 512
#define WW 512
#define WT 64
#define NT 768             // 12 waves
#define PITCH 305          // tile slot pitch
#define HLN 304
#define NROW 268           // computed rows (256 out + 12 halo)

typedef _Float16 half4_t __attribute__((ext_vector_type(4)));

__device__ __forceinline__ float dpp_prev(float v) {   // lane i <- lane i-1
    return __int_as_float(__builtin_amdgcn_update_dpp(
        0, __float_as_int(v), 0x138, 0xf, 0xf, false)); // wave_shr:1, edge->0
}
__device__ __forceinline__ float dpp_next(float v) {   // lane i <- lane i+1
    return __int_as_float(__builtin_amdgcn_update_dpp(
        0, __float_as_int(v), 0x130, 0xf, 0xf, false)); // wave_shl:1, edge->0
}

// LDS-only barrier: drains lgkm (ds_write visibility), leaves vmem in flight.
__device__ __forceinline__ void lds_barrier() {
    asm volatile("s_waitcnt lgkmcnt(0)" ::: "memory");
    __builtin_amdgcn_s_barrier();
    __builtin_amdgcn_sched_barrier(0);
}

__device__ __forceinline__ half4_t norm_pack(float xx, float g1, float g2, float g3) {
    const float sa = fabsf(g1) + fabsf(g2) + fabsf(g3);
    const float sc = (sa >= 1.0f) ? (1.0f / sa) : 1.0f;
    const float n1 = g1 * sc, n2 = g2 * sc, n3 = g3 * sc;
    const float a  = 1.0f - n1 - n2 - n3;
    half4_t v;
    v.x = (_Float16)(a * xx);
    v.y = (_Float16)n1;
    v.z = (_Float16)n2;
    v.w = (_Float16)n3;
    return v;
}

__global__ __launch_bounds__(NT, 1) void spn_kernel(
    const float* __restrict__ X, const float* __restrict__ G1,
    const float* __restrict__ G2, const float* __restrict__ G3,
    float* __restrict__ OUT)
{
    extern __shared__ char smem[];
    half4_t* tile = (half4_t*)smem;                            // [64][PITCH]
    float*   hlA  = (float*)(smem + (size_t)WT * PITCH * 8);   // [HLN] x2
    float*   hlB  = hlA + HLN;

    const int tid = threadIdx.x;
    const int wv  = tid >> 6;
    const int L   = tid & 63;
    const bool act = (wv < 6);               // scan waves
    const int cr   = act ? (48 * wv + L - 8) : 0;   // -8 .. 295
    const int slot = cr + 8;                 // 0 .. 303
    const bool owned = act && (L >= 8) && (L < 56);

    const int slice = blockIdx.x >> 2;
    const int wch   = blockIdx.x & 1;
    const int hch   = (blockIdx.x >> 1) & 1;
    const int cend   = wch ? WW : 320;       // scan region right edge
    const int ntiles = wch ? 4 : 5;
    const int warm   = wch ? 0 : 1;          // wch0's first tile = warmup
    const int hb     = hch ? (HH - NROW) : 0;
    const int out_lo = hch ? 256 : 0;
    const int out_hi = hch ? 512 : 256;
    const int crg    = hb + cr;
    const bool do_store = owned && (crg >= out_lo) && (crg < out_hi);

    const size_t base = (size_t)slice * (size_t)(HH * WW);
    const float* Xp  = X  + base;
    const float* G1p = G1 + base;
    const float* G2p = G2 + base;
    const float* G3p = G3 + base;
    float* Op = OUT + base;

    // one-time zero-fill: tile edge slots (0..7, 276..304 for all 64 w) and
    // both h-lines; visible at the first post-stage barrier.
    {
        half4_t z; z.x = (_Float16)0; z.y = (_Float16)0; z.z = (_Float16)0; z.w = (_Float16)0;
        for (int i = tid; i < WT * 37; i += NT) {
            const int w = i / 37, k = i % 37;
            const int s = (k < 8) ? k : (268 + k);   // 0..7, 276..304
            tile[w * PITCH + s] = z;
        }
        for (int i = tid; i < 2 * HLN; i += NT) hlA[i] = 0.0f;
    }

    const int lq = tid & 15;   // float4 sixteenth of a row's 256B segment
    const int lr = tid >> 4;   // staging row within a 48-row round

    for (int t = 0; t < ntiles; ++t) {
        const int w0 = cend - WT * (t + 1);
        const bool emit = (t >= warm);

        // ---- stage tile t: 268 rows x 256B x 4 arrays, fp16-packed ----
        #pragma unroll
        for (int j = 0; j < 6; ++j) {
            const int ri = 48 * j + lr;
            if (j < 5 || ri < NROW) {
                const size_t off = (size_t)(hb + ri) * WW + (size_t)(w0 + 4 * lq);
                const float4 x  = *(const float4*)(Xp  + off);
                const float4 a1 = *(const float4*)(G1p + off);
                const float4 a2 = *(const float4*)(G2p + off);
                const float4 a3 = *(const float4*)(G3p + off);
                const int s = ri + 8;
                tile[(4 * lq + 0) * PITCH + s] = norm_pack(x.x, a1.x, a2.x, a3.x);
                tile[(4 * lq + 1) * PITCH + s] = norm_pack(x.y, a1.y, a2.y, a3.y);
                tile[(4 * lq + 2) * PITCH + s] = norm_pack(x.z, a1.z, a2.z, a3.z);
                tile[(4 * lq + 3) * PITCH + s] = norm_pack(x.w, a1.w, a2.w, a3.w);
            }
        }
        lds_barrier();   // tile visible; vmem not drained

        // ---- scan: 8 sub-phases x 8 barrier-free DPP steps (waves 0-5) ----
        float hv[WT];
        #pragma unroll
        for (int sub = 0; sub < 8; ++sub) {
            const float* rd = (sub & 1) ? hlB : hlA;
            float*       wr = (sub & 1) ? hlA : hlB;
            if (act) {
                float h = rd[slot];
                #pragma unroll
                for (int s = 0; s < 8; ++s) {
                    const int q = WT - 1 - 8 * sub - s;
                    const half4_t v = tile[q * PITCH + slot];
                    const float hu = dpp_prev(h);
                    const float hd = dpp_next(h);
                    h = fmaf((float)v.y, hu,
                        fmaf((float)v.z, h,
                        fmaf((float)v.w, hd, (float)v.x)));
                    hv[q] = h;
                }
                if (owned) wr[slot] = h;
            }
            lds_barrier();
        }
        // 8 sub-phases (even) -> next tile's sub0 reads hlA again

        // ---- 256B contiguous output stores ----
        if (do_store && emit) {
            float* bo = Op + (size_t)crg * WW + (size_t)w0;
            #pragma unroll
            for (int j = 0; j < 16; ++j)
                *(float4*)(bo + 4 * j) = make_float4(hv[4 * j + 0], hv[4 * j + 1],
                                                     hv[4 * j + 2], hv[4 * j + 3]);
        }
    }
}

extern "C" void kernel_launch(void* const* d_in, const int* in_sizes, int n_in,
                              void* d_out, int out_size, void* d_ws, size_t ws_size,
                              hipStream_t stream) {
    const float* X  = (const float*)d_in[0];
    const float* G1 = (const float*)d_in[1];
    const float* G2 = (const float*)d_in[2];
    const float* G3 = (const float*)d_in[3];
    float* OUT = (float*)d_out;

    const int nblocks = 4 * 32 * 4;   // 128 slices x 2 W-chunks x 2 H-halves
    const size_t smem = (size_t)WT * PITCH * 8 + 2 * HLN * sizeof(float); // 158592B

    (void)hipFuncSetAttribute((const void*)spn_kernel,
                              hipFuncAttributeMaxDynamicSharedMemorySize, (int)smem);

    spn_kernel<<<nblocks, NT, smem, stream>>>(X, G1, G2, G3, OUT);
}